// Round 7
// baseline (1077.362 us; speedup 1.0000x reference)
//
#include <hip/hip_runtime.h>
#include <hip/hip_bf16.h>

typedef __attribute__((ext_vector_type(8))) short bf16x8;
typedef __attribute__((ext_vector_type(4))) float f32x4;

static __device__ __forceinline__ short f2bf(float f) {
    __hip_bfloat16 h = __float2bfloat16(f);
    return *reinterpret_cast<short*>(&h);
}

// ---------------- fp32 -> bf16 conversion ---------------------------------
__global__ void cvt_f32_bf16(const float* __restrict__ src,
                             short* __restrict__ dst, long long n) {
    long long i = ((long long)blockIdx.x * blockDim.x + threadIdx.x) * 8;
    const long long stride = (long long)gridDim.x * blockDim.x * 8;
    for (; i < n; i += stride) {
        f32x4 x = *reinterpret_cast<const f32x4*>(src + i);
        f32x4 y = *reinterpret_cast<const f32x4*>(src + i + 4);
        bf16x8 v;
        v[0] = f2bf(x[0]); v[1] = f2bf(x[1]); v[2] = f2bf(x[2]); v[3] = f2bf(x[3]);
        v[4] = f2bf(y[0]); v[5] = f2bf(y[1]); v[6] = f2bf(y[2]); v[7] = f2bf(y[3]);
        *reinterpret_cast<bf16x8*>(dst + i) = v;
    }
}

static __device__ __forceinline__ void gload_lds16(const short* g, short* l) {
    __builtin_amdgcn_global_load_lds(
        (const __attribute__((address_space(1))) void*)g,
        (__attribute__((address_space(3))) void*)l, 16, 0, 0);
}

// ============== 256x256 fused GEMM + CE partials — m201 8-phase port =======
// 512 thr = 8 waves (2x4). BK=64, dbuf LDS 128 KiB. 2 K-tiles per 8-phase
// iteration. Per phase: {ds_read cluster ; stage 1 half-tile ; [vmcnt @4,8]
// ; barrier ; lgkmcnt(0) ; setprio(1) ; 16 MFMA ; setprio(0) ; barrier}.
// vmcnt(6) = 2 loads/half-tile x 3 half-tiles in flight (counted, never 0
// in steady state). Stage targets verified: each region staged >=1 barrier
// after its last reader; each vmcnt(6) completes the next tile fully.
// LDS swizzle: 16B chunk c of row r at c^(r&7); pre-swizzled global source,
// reads XOR same involution (measured: 0 bank conflicts).

#define STAGE_A(buf, h, tt) do { \
    gload_lds16(aSrc + (size_t)(h) * H128 + (size_t)(tt) * 64, \
                As_s + ((buf) << 14) + (h) * 8192 + w * 1024); \
    gload_lds16(aSrc + (size_t)(h) * H128 + H8 + (size_t)(tt) * 64, \
                As_s + ((buf) << 14) + (h) * 8192 + w * 1024 + 512); \
} while (0)

#define STAGE_B(buf, h, tt) do { \
    gload_lds16(bSrc + (size_t)(h) * H128 + (size_t)(tt) * 64, \
                Bs_s + ((buf) << 14) + (h) * 8192 + w * 1024); \
    gload_lds16(bSrc + (size_t)(h) * H128 + H8 + (size_t)(tt) * 64, \
                Bs_s + ((buf) << 14) + (h) * 8192 + w * 1024 + 512); \
} while (0)

#define LDA(P, m, ks) (*reinterpret_cast<const bf16x8*>( \
    (P) + aRow + ((m) & 3) * 1024 + ((m) >> 2) * 8192 + ((ks) ? cK1 : cK0)))
#define LDB(P, n, ks) (*reinterpret_cast<const bf16x8*>( \
    (P) + bRow + (n) * 1024 + ((ks) ? cK1 : cK0)))

// barrier -> lgkmcnt(0) -> sched fence (rule 18) -> prio up
#define PH_MID() do { \
    __builtin_amdgcn_sched_barrier(0); \
    __builtin_amdgcn_s_barrier(); \
    asm volatile("s_waitcnt lgkmcnt(0)" ::: "memory"); \
    __builtin_amdgcn_sched_barrier(0); \
    __builtin_amdgcn_s_setprio(1); \
} while (0)

#define PH_TAIL() do { \
    __builtin_amdgcn_s_setprio(0); \
    __builtin_amdgcn_sched_barrier(0); \
    __builtin_amdgcn_s_barrier(); \
} while (0)

// 16 MFMA: m-pair (mb, mb+1) x 4n x 2ks; ks-grouped so each acc reg has
// dependency distance 8.
#define MFMA16(mb) do { \
    _Pragma("unroll") \
    for (int n = 0; n < 4; ++n) { \
        acc[(mb)][n]   = __builtin_amdgcn_mfma_f32_16x16x32_bf16(aa0, bfr[n][0], acc[(mb)][n],   0, 0, 0); \
        acc[(mb)+1][n] = __builtin_amdgcn_mfma_f32_16x16x32_bf16(aa2, bfr[n][0], acc[(mb)+1][n], 0, 0, 0); \
    } \
    _Pragma("unroll") \
    for (int n = 0; n < 4; ++n) { \
        acc[(mb)][n]   = __builtin_amdgcn_mfma_f32_16x16x32_bf16(aa1, bfr[n][1], acc[(mb)][n],   0, 0, 0); \
        acc[(mb)+1][n] = __builtin_amdgcn_mfma_f32_16x16x32_bf16(aa3, bfr[n][1], acc[(mb)+1][n], 0, 0, 0); \
    } \
} while (0)

// FULL iteration: computes tiles T (buf0), T+1 (buf1); stages T+2, T+3.
#define FULL_ITER(T) do { \
    bf16x8 bfr[4][2]; \
    { /* ph1: B[buf0] + A m0,m1 ; stage A1[T+1] -> buf1 */ \
      _Pragma("unroll") \
      for (int n = 0; n < 4; ++n) { bfr[n][0] = LDB(Bb0, n, 0); bfr[n][1] = LDB(Bb0, n, 1); } \
      bf16x8 aa0 = LDA(Ab0, 0, 0), aa1 = LDA(Ab0, 0, 1), aa2 = LDA(Ab0, 1, 0), aa3 = LDA(Ab0, 1, 1); \
      STAGE_A(1, 1, (T) + 1); \
      asm volatile("s_waitcnt lgkmcnt(8)" ::: "memory"); \
      PH_MID(); MFMA16(0); PH_TAIL(); \
    } \
    { /* ph2: A m2,m3 ; stage B0[T+2] -> buf0 */ \
      bf16x8 aa0 = LDA(Ab0, 2, 0), aa1 = LDA(Ab0, 2, 1), aa2 = LDA(Ab0, 3, 0), aa3 = LDA(Ab0, 3, 1); \
      STAGE_B(0, 0, (T) + 2); \
      PH_MID(); MFMA16(2); PH_TAIL(); \
    } \
    { /* ph3: A m4,m5 ; stage B1[T+2] */ \
      bf16x8 aa0 = LDA(Ab0, 4, 0), aa1 = LDA(Ab0, 4, 1), aa2 = LDA(Ab0, 5, 0), aa3 = LDA(Ab0, 5, 1); \
      STAGE_B(0, 1, (T) + 2); \
      PH_MID(); MFMA16(4); PH_TAIL(); \
    } \
    { /* ph4: A m6,m7 ; stage A0[T+2] ; vmcnt(6) */ \
      bf16x8 aa0 = LDA(Ab0, 6, 0), aa1 = LDA(Ab0, 6, 1), aa2 = LDA(Ab0, 7, 0), aa3 = LDA(Ab0, 7, 1); \
      STAGE_A(0, 0, (T) + 2); \
      asm volatile("s_waitcnt vmcnt(6)" ::: "memory"); \
      PH_MID(); MFMA16(6); PH_TAIL(); \
    } \
    { /* ph5: B[buf1] + A m0,m1 ; stage A1[T+2] -> buf0 */ \
      _Pragma("unroll") \
      for (int n = 0; n < 4; ++n) { bfr[n][0] = LDB(Bb1, n, 0); bfr[n][1] = LDB(Bb1, n, 1); } \
      bf16x8 aa0 = LDA(Ab1, 0, 0), aa1 = LDA(Ab1, 0, 1), aa2 = LDA(Ab1, 1, 0), aa3 = LDA(Ab1, 1, 1); \
      STAGE_A(0, 1, (T) + 2); \
      asm volatile("s_waitcnt lgkmcnt(8)" ::: "memory"); \
      PH_MID(); MFMA16(0); PH_TAIL(); \
    } \
    { /* ph6: A m2,m3 ; stage B0[T+3] -> buf1 */ \
      bf16x8 aa0 = LDA(Ab1, 2, 0), aa1 = LDA(Ab1, 2, 1), aa2 = LDA(Ab1, 3, 0), aa3 = LDA(Ab1, 3, 1); \
      STAGE_B(1, 0, (T) + 3); \
      PH_MID(); MFMA16(2); PH_TAIL(); \
    } \
    { /* ph7: A m4,m5 ; stage B1[T+3] */ \
      bf16x8 aa0 = LDA(Ab1, 4, 0), aa1 = LDA(Ab1, 4, 1), aa2 = LDA(Ab1, 5, 0), aa3 = LDA(Ab1, 5, 1); \
      STAGE_B(1, 1, (T) + 3); \
      PH_MID(); MFMA16(4); PH_TAIL(); \
    } \
    { /* ph8: A m6,m7 ; stage A0[T+3] ; vmcnt(6) */ \
      bf16x8 aa0 = LDA(Ab1, 6, 0), aa1 = LDA(Ab1, 6, 1), aa2 = LDA(Ab1, 7, 0), aa3 = LDA(Ab1, 7, 1); \
      STAGE_A(1, 0, (T) + 3); \
      asm volatile("s_waitcnt vmcnt(6)" ::: "memory"); \
      PH_MID(); MFMA16(6); PH_TAIL(); \
    } \
} while (0)

// LAST iteration: computes tiles T, T+1; only stage is A1[T+1] at ph1.
#define LAST_ITER(T) do { \
    bf16x8 bfr[4][2]; \
    { _Pragma("unroll") \
      for (int n = 0; n < 4; ++n) { bfr[n][0] = LDB(Bb0, n, 0); bfr[n][1] = LDB(Bb0, n, 1); } \
      bf16x8 aa0 = LDA(Ab0, 0, 0), aa1 = LDA(Ab0, 0, 1), aa2 = LDA(Ab0, 1, 0), aa3 = LDA(Ab0, 1, 1); \
      STAGE_A(1, 1, (T) + 1); \
      asm volatile("s_waitcnt lgkmcnt(8)" ::: "memory"); \
      PH_MID(); MFMA16(0); PH_TAIL(); \
    } \
    { bf16x8 aa0 = LDA(Ab0, 2, 0), aa1 = LDA(Ab0, 2, 1), aa2 = LDA(Ab0, 3, 0), aa3 = LDA(Ab0, 3, 1); \
      PH_MID(); MFMA16(2); PH_TAIL(); \
    } \
    { bf16x8 aa0 = LDA(Ab0, 4, 0), aa1 = LDA(Ab0, 4, 1), aa2 = LDA(Ab0, 5, 0), aa3 = LDA(Ab0, 5, 1); \
      PH_MID(); MFMA16(4); PH_TAIL(); \
    } \
    { bf16x8 aa0 = LDA(Ab0, 6, 0), aa1 = LDA(Ab0, 6, 1), aa2 = LDA(Ab0, 7, 0), aa3 = LDA(Ab0, 7, 1); \
      asm volatile("s_waitcnt vmcnt(2)" ::: "memory"); \
      PH_MID(); MFMA16(6); PH_TAIL(); \
    } \
    { _Pragma("unroll") \
      for (int n = 0; n < 4; ++n) { bfr[n][0] = LDB(Bb1, n, 0); bfr[n][1] = LDB(Bb1, n, 1); } \
      bf16x8 aa0 = LDA(Ab1, 0, 0), aa1 = LDA(Ab1, 0, 1), aa2 = LDA(Ab1, 1, 0), aa3 = LDA(Ab1, 1, 1); \
      PH_MID(); MFMA16(0); PH_TAIL(); \
    } \
    { bf16x8 aa0 = LDA(Ab1, 2, 0), aa1 = LDA(Ab1, 2, 1), aa2 = LDA(Ab1, 3, 0), aa3 = LDA(Ab1, 3, 1); \
      asm volatile("s_waitcnt vmcnt(0)" ::: "memory"); \
      PH_MID(); MFMA16(2); PH_TAIL(); \
    } \
    { bf16x8 aa0 = LDA(Ab1, 4, 0), aa1 = LDA(Ab1, 4, 1), aa2 = LDA(Ab1, 5, 0), aa3 = LDA(Ab1, 5, 1); \
      PH_MID(); MFMA16(4); PH_TAIL(); \
    } \
    { bf16x8 aa0 = LDA(Ab1, 6, 0), aa1 = LDA(Ab1, 6, 1), aa2 = LDA(Ab1, 7, 0), aa3 = LDA(Ab1, 7, 1); \
      PH_MID(); MFMA16(6); PH_TAIL(); \
    } \
} while (0)

__global__ __launch_bounds__(512, 2) void ce_gemm_bf16_256(
    const short* __restrict__ inp, const short* __restrict__ wgt,
    const int* __restrict__ target,
    float* __restrict__ pm, float* __restrict__ ps, float* __restrict__ tgt,
    int H, int Mt, int Vt)
{
    __shared__ __align__(16) char smem[131072];
    short* As_s = (short*)smem;              // [2][256][64] bf16 = 64 KiB
    short* Bs_s = (short*)(smem + 65536);    // 64 KiB

    const int NT = H >> 6;          // K-tiles (even, >=4)
    const int NI = NT >> 1;         // 8-phase iterations

    // bijective XCD swizzle; mt fastest within an XCD chunk
    const int nwg = Mt * Vt;
    const int orig = blockIdx.x;
    const int q8 = nwg >> 3, r8 = nwg & 7;
    const int xcd = orig & 7, idx = orig >> 3;
    const int wg = (xcd < r8 ? xcd * (q8 + 1) : r8 * (q8 + 1) + (xcd - r8) * q8) + idx;
    const int vt = wg / Mt;
    const int mt = wg - vt * Mt;
    const int m0 = mt * 256;
    const int v0 = vt * 256;

    const int tid  = threadIdx.x;
    const int lane = tid & 63;
    const int w    = tid >> 6;     // wave 0..7
    const int wr   = w >> 2;       // 0..1 row-wave
    const int wc   = w & 3;        // 0..3 col-wave

    const size_t H8   = (size_t)H * 8;
    const size_t H128 = (size_t)H * 128;

    // staging source (global, pre-swizzled chunk)
    const short* aSrc = inp + (size_t)(m0 + w * 16 + (lane >> 3)) * H
                        + ((lane & 7) ^ (lane >> 3)) * 8;
    const short* bSrc = wgt + (size_t)(v0 + w * 16 + (lane >> 3)) * H
                        + ((lane & 7) ^ (lane >> 3)) * 8;

    // LDS read bases
    const short* Ab0 = As_s;
    const short* Ab1 = As_s + 16384;
    const short* Bb0 = Bs_s;
    const short* Bb1 = Bs_s + 16384;
    const int aRow = (wr * 64 + (lane & 15)) * 64;
    const int bRow = (wc * 64 + (lane & 15)) * 64;
    const int cK0 = ((lane >> 4) ^ (lane & 7)) * 8;
    const int cK1 = ((4 | (lane >> 4)) ^ (lane & 7)) * 8;

    f32x4 acc[8][4] = {};

    // ---- prologue: tile0 (4 half-tiles), vmcnt(4), tile1 (3), vmcnt(6) ----
    STAGE_B(0, 0, 0);
    STAGE_B(0, 1, 0);
    STAGE_A(0, 0, 0);
    STAGE_A(0, 1, 0);
    asm volatile("s_waitcnt vmcnt(4)" ::: "memory");
    STAGE_B(1, 0, 1);
    STAGE_B(1, 1, 1);
    STAGE_A(1, 0, 1);
    asm volatile("s_waitcnt vmcnt(6)" ::: "memory");
    __builtin_amdgcn_s_barrier();
    __builtin_amdgcn_sched_barrier(0);

    for (int j = 0; j < NI - 1; ++j)
        FULL_ITER(2 * j);
    LAST_ITER(NT - 2);

    // ================= epilogue: fused CE partials =========================
    float* lmax = (float*)smem;
    float* lsum = (float*)(smem + 4096);
    int*   st   = (int*)(smem + 8192);
    __syncthreads();
    if (tid < 256) st[tid] = target[m0 + tid];
    __syncthreads();

    const int g = lane >> 4, c0e = lane & 15;
    #pragma unroll
    for (int m = 0; m < 8; ++m) {
        const int rowbase = ((m >> 2) * 128) + wr * 64 + (m & 3) * 16;
        #pragma unroll
        for (int j = 0; j < 4; ++j) {
            const int row = rowbase + g * 4 + j;
            float vmax = fmaxf(fmaxf(acc[m][0][j], acc[m][1][j]),
                               fmaxf(acc[m][2][j], acc[m][3][j]));
            #pragma unroll
            for (int d = 1; d < 16; d <<= 1)
                vmax = fmaxf(vmax, __shfl_xor(vmax, d));
            float s = 0.f;
            #pragma unroll
            for (int n = 0; n < 4; ++n)
                s += expf(acc[m][n][j] - vmax);
            #pragma unroll
            for (int d = 1; d < 16; d <<= 1)
                s += __shfl_xor(s, d);
            const int tg = st[row];
            #pragma unroll
            for (int n = 0; n < 4; ++n) {
                if (v0 + wc * 64 + n * 16 + c0e == tg)
                    tgt[m0 + row] = acc[m][n][j];
            }
            if (c0e == 0) { lmax[wc * 256 + row] = vmax; lsum[wc * 256 + row] = s; }
        }
    }
    __syncthreads();
    if (tid < 256) {
        float M = lmax[tid];
        M = fmaxf(M, lmax[256 + tid]);
        M = fmaxf(M, lmax[512 + tid]);
        M = fmaxf(M, lmax[768 + tid]);
        float S = lsum[tid]       * expf(lmax[tid]       - M)
                + lsum[256 + tid] * expf(lmax[256 + tid] - M)
                + lsum[512 + tid] * expf(lmax[512 + tid] - M)
                + lsum[768 + tid] * expf(lmax[768 + tid] - M);
        const size_t o = (size_t)(m0 + tid) * Vt + vt;
        pm[o] = M;
        ps[o] = S;
    }
}

// ---------------- fallback path: fp32 reg-staged 128^2 --------------------
#define TILE 128
#define BK 64
static __device__ __forceinline__ void stage_tile(
    const float* __restrict__ src, long long ld, int row0, int k0,
    short (*__restrict__ dst)[BK], int tid)
{
    const int r = tid >> 1;
    const int h = (tid & 1) * 32;
    const float* p = src + (long long)(row0 + r) * ld + k0 + h;
    #pragma unroll
    for (int j = 0; j < 4; ++j) {
        f32x4 x = *reinterpret_cast<const f32x4*>(p + j * 8);
        f32x4 y = *reinterpret_cast<const f32x4*>(p + j * 8 + 4);
        bf16x8 v;
        v[0] = f2bf(x[0]); v[1] = f2bf(x[1]); v[2] = f2bf(x[2]); v[3] = f2bf(x[3]);
        v[4] = f2bf(y[0]); v[5] = f2bf(y[1]); v[6] = f2bf(y[2]); v[7] = f2bf(y[3]);
        *reinterpret_cast<bf16x8*>(&dst[r][h + j * 8]) = v;
    }
}

__global__ __launch_bounds__(256, 2) void ce_gemm_partial(
    const float* __restrict__ inp, const float* __restrict__ wgt,
    const int* __restrict__ target,
    float* __restrict__ pm, float* __restrict__ ps, float* __restrict__ tgt,
    int H, int Vt)
{
    __shared__ __align__(16) short As2[TILE][BK];
    __shared__ __align__(16) short Bs2[TILE][BK];
    __shared__ float lmax[2][TILE];
    __shared__ float lsum[2][TILE];
    __shared__ int st[TILE];

    const int tid  = threadIdx.x;
    const int lane = tid & 63;
    const int wid  = tid >> 6;
    const int wrow = wid >> 1;
    const int wcol = wid & 1;
    const int m0 = blockIdx.x * TILE;
    const int v0 = blockIdx.y * TILE;
    const int vt = blockIdx.y;

    if (tid < TILE) st[tid] = target[m0 + tid];

    f32x4 acc[4][4] = {};

    for (int k0 = 0; k0 < H; k0 += BK) {
        stage_tile(inp, H, m0, k0, As2, tid);
        stage_tile(wgt, H, v0, k0, Bs2, tid);
        __syncthreads();
        #pragma unroll
        for (int ks = 0; ks < 2; ++ks) {
            const int kk = ks * 32 + ((lane >> 4) << 3);
            bf16x8 a[4], b[4];
            #pragma unroll
            for (int m = 0; m < 4; ++m)
                a[m] = *reinterpret_cast<const bf16x8*>(&As2[wrow * 64 + m * 16 + (lane & 15)][kk]);
            #pragma unroll
            for (int n = 0; n < 4; ++n)
                b[n] = *reinterpret_cast<const bf16x8*>(&Bs2[wcol * 64 + n * 16 + (lane & 15)][kk]);
            #pragma unroll
            for (int m = 0; m < 4; ++m)
                #pragma unroll
                for (int n = 0; n < 4; ++n)
                    acc[m][n] = __builtin_amdgcn_mfma_f32_16x16x32_bf16(a[m], b[n], acc[m][n], 0, 0, 0);
        }
        __syncthreads();
    }

    const int g = lane >> 4, c0 = lane & 15;
    #pragma unroll
    for (int m = 0; m < 4; ++m) {
        #pragma unroll
        for (int j = 0; j < 4; ++j) {
            float vmax = fmaxf(fmaxf(acc[m][0][j], acc[m][1][j]),
                               fmaxf(acc[m][2][j], acc[m][3][j]));
            #pragma unroll
            for (int d = 1; d < 16; d <<= 1)
                vmax = fmaxf(vmax, __shfl_xor(vmax, d));
            float s = 0.f;
            #pragma unroll
            for (int n = 0; n < 4; ++n)
                s += expf(acc[m][n][j] - vmax);
            #pragma unroll
            for (int d = 1; d < 16; d <<= 1)
                s += __shfl_xor(s, d);
            const int row = wrow * 64 + m * 16 + g * 4 + j;
            const int t = st[row];
            #pragma unroll
            for (int n = 0; n < 4; ++n) {
                if (v0 + wcol * 64 + n * 16 + c0 == t)
                    tgt[m0 + row] = acc[m][n][j];
            }
            if (c0 == 0) { lmax[wcol][row] = vmax; lsum[wcol][row] = s; }
        }
    }
    __syncthreads();
    if (tid < TILE) {
        const float ma = lmax[0][tid], mb = lmax[1][tid];
        const float M = fmaxf(ma, mb);
        const float S = lsum[0][tid] * expf(ma - M) + lsum[1][tid] * expf(mb - M);
        const size_t idx = (size_t)(m0 + tid) * Vt + vt;
        pm[idx] = M;
        ps[idx] = S;
    }
}

// ---------------- reductions ----------------------------------------------
__global__ void ce_reduce_rows(
    const float* __restrict__ pm, const float* __restrict__ ps,
    const float* __restrict__ tgt, const int* __restrict__ target,
    float* __restrict__ rownll, float* __restrict__ rowvalid, int Vt, int V)
{
    const int row = blockIdx.x;
    const int lane = threadIdx.x;
    float m = -1e30f, s = 0.f;
    for (int vt = lane; vt < Vt; vt += 64) {
        const size_t idx = (size_t)row * Vt + vt;
        const float pmv = pm[idx], psv = ps[idx];
        const float M = fmaxf(m, pmv);
        s = s * expf(m - M) + psv * expf(pmv - M);
        m = M;
    }
    #pragma unroll
    for (int d = 1; d < 64; d <<= 1) {
        const float om = __shfl_xor(m, d), os = __shfl_xor(s, d);
        const float M = fmaxf(m, om);
        s = s * expf(m - M) + os * expf(om - M);
        m = M;
    }
    if (lane == 0) {
        const int t = target[row];
        const bool valid = (t >= 0 && t < V);
        rownll[row]   = valid ? (m + logf(s) - tgt[row]) : 0.f;
        rowvalid[row] = valid ? 1.f : 0.f;
    }
}

__global__ void ce_final(
    const float* __restrict__ rownll, const float* __restrict__ rowvalid,
    float* __restrict__ out, int BT)
{
    __shared__ float ssum[256];
    __shared__ float scnt[256];
    const int tid = threadIdx.x;
    float a = 0.f, c = 0.f;
    for (int i = tid; i < BT; i += 256) { a += rownll[i]; c += rowvalid[i]; }
    ssum[tid] = a; scnt[tid] = c;
    __syncthreads();
    for (int d = 128; d; d >>= 1) {
        if (tid < d) { ssum[tid] += ssum[tid + d]; scnt[tid] += scnt[tid + d]; }
        __syncthreads();
    }
    if (tid == 0) out[0] = ssum[0] / fmaxf(scnt[0], 1.f);
}

extern "C" void kernel_launch(void* const* d_in, const int* in_sizes, int n_in,
                              void* d_out, int out_size, void* d_ws, size_t ws_size,
                              hipStream_t stream) {
    (void)n_in; (void)out_size;
    const float* inp    = (const float*)d_in[0];
    const float* wgt    = (const float*)d_in[1];
    const int*   target = (const int*)d_in[2];
    float* out = (float*)d_out;

    const int BT = in_sizes[2];
    const int H  = in_sizes[0] / BT;
    const int V  = (int)((long long)in_sizes[1] / H);

    const size_t wbf_bytes = (size_t)V * H * 2;
    const size_t ibf_bytes = (size_t)BT * H * 2;

    const bool ok256 = (BT % 256 == 0) && (V % 256 == 0) && (H % 128 == 0) && (H >= 256);

    char* ws = (char*)d_ws;
    if (ok256) {
        const int Mt = BT / 256;   // 16
        const int Vt = V / 256;    // 125
        const size_t pm_bytes = (size_t)BT * Vt * 4;
        const size_t small    = (size_t)BT * 4;
        const size_t need = wbf_bytes + ibf_bytes + 2 * pm_bytes + 3 * small;
        if (ws_size >= need) {
            short* wbf = (short*)ws;                      size_t o = wbf_bytes;
            short* ibf = (short*)(ws + o);                o += ibf_bytes;
            float* pm       = (float*)(ws + o);           o += pm_bytes;
            float* ps       = (float*)(ws + o);           o += pm_bytes;
            float* tgt      = (float*)(ws + o);           o += small;
            float* rownll   = (float*)(ws + o);           o += small;
            float* rowvalid = (float*)(ws + o);

            cvt_f32_bf16<<<2048, 256, 0, stream>>>(wgt, wbf, (long long)V * H);
            cvt_f32_bf16<<<512, 256, 0, stream>>>(inp, ibf, (long long)BT * H);
            ce_gemm_bf16_256<<<Mt * Vt, 512, 0, stream>>>(ibf, wbf, target, pm, ps, tgt, H, Mt, Vt);
            ce_reduce_rows<<<BT, 64, 0, stream>>>(pm, ps, tgt, target, rownll, rowvalid, Vt, V);
            ce_final<<<1, 256, 0, stream>>>(rownll, rowvalid, out, BT);
            return;
        }
    }
    // fallback: fp32 reg-staged 128^2
    {
        const int Mt = BT / TILE;
        const int Vt = V / TILE;
        const size_t pm_bytes = (size_t)BT * Vt * 4;
        const size_t small    = (size_t)BT * 4;
        float* pm       = (float*)ws;                 size_t o = pm_bytes;
        float* ps       = (float*)(ws + o);           o += pm_bytes;
        float* tgt      = (float*)(ws + o);           o += small;
        float* rownll   = (float*)(ws + o);           o += small;
        float* rowvalid = (float*)(ws + o);

        dim3 grid(Mt, Vt);
        ce_gemm_partial<<<grid, 256, 0, stream>>>(inp, wgt, target, pm, ps, tgt, H, Vt);
        ce_reduce_rows<<<BT, 64, 0, stream>>>(pm, ps, tgt, target, rownll, rowvalid, Vt, V);
        ce_final<<<1, 256, 0, stream>>>(rownll, rowvalid, out, BT);
    }
}

// Round 8
// 1069.985 us; speedup vs baseline: 1.0069x; 1.0069x over previous
//
#include <hip/hip_runtime.h>
#include <hip/hip_bf16.h>

typedef __attribute__((ext_vector_type(8))) short bf16x8;
typedef __attribute__((ext_vector_type(4))) float f32x4;

static __device__ __forceinline__ short f2bf(float f) {
    __hip_bfloat16 h = __float2bfloat16(f);
    return *reinterpret_cast<short*>(&h);
}

// ---------------- fp32 -> bf16 conversion ---------------------------------
__global__ void cvt_f32_bf16(const float* __restrict__ src,
                             short* __restrict__ dst, long long n) {
    long long i = ((long long)blockIdx.x * blockDim.x + threadIdx.x) * 8;
    const long long stride = (long long)gridDim.x * blockDim.x * 8;
    for (; i < n; i += stride) {
        f32x4 x = *reinterpret_cast<const f32x4*>(src + i);
        f32x4 y = *reinterpret_cast<const f32x4*>(src + i + 4);
        bf16x8 v;
        v[0] = f2bf(x[0]); v[1] = f2bf(x[1]); v[2] = f2bf(x[2]); v[3] = f2bf(x[3]);
        v[4] = f2bf(y[0]); v[5] = f2bf(y[1]); v[6] = f2bf(y[2]); v[7] = f2bf(y[3]);
        *reinterpret_cast<bf16x8*>(dst + i) = v;
    }
}

static __device__ __forceinline__ void gload_lds16(const short* g, short* l) {
    __builtin_amdgcn_global_load_lds(
        (const __attribute__((address_space(1))) void*)g,
        (__attribute__((address_space(3))) void*)l, 16, 0, 0);
}

// ============== 256x256 fused GEMM + CE partials ===========================
// Round-6 skeleton (best: 950us, 53.5% MfmaUtil, 0 conflicts), with the
// per-phase sched_barrier(0) pins around MFMA clusters REMOVED so the
// compiler can interleave ds_reads / global_load_lds into the MFMA clusters.
// Boundary ordering is preserved by: asm vmcnt (memory clobber) + s_barrier
// + one sched_barrier(0) per tile. Intra-tile reorder is safe: stagings
// write nxt, reads target cur.
// Phases: ph0=m0-3/ks0, ph1=m4-7/ks0, ph2=m0-3/ks1, ph3=m4-7/ks1; read
// clusters 8/4/8/4 issued one phase ahead. Stage one half-tile per phase
// into nxt. vmcnt(0) mid-tile (drains Ah1[cur], issued a full tile ago ->
// free); boundary vmcnt(2) (leaves Ah1[t+1] in flight); 1 barrier/tile.
// LDS swizzle: 16B chunk c of row r stored at c^(r&7); global source
// pre-swizzled, reads XOR the same involution (verified: 0 conflicts).

#define STAGE_A(buf, h, tt) do { \
    gload_lds16(aSrc + (size_t)(h) * H128 + (size_t)(tt) * 64, \
                As_s + ((buf) << 14) + (h) * 8192 + w * 1024); \
    gload_lds16(aSrc + (size_t)(h) * H128 + H8 + (size_t)(tt) * 64, \
                As_s + ((buf) << 14) + (h) * 8192 + w * 1024 + 512); \
} while (0)

#define STAGE_B(buf, h, tt) do { \
    gload_lds16(bSrc + (size_t)(h) * H128 + (size_t)(tt) * 64, \
                Bs_s + ((buf) << 14) + (h) * 8192 + w * 1024); \
    gload_lds16(bSrc + (size_t)(h) * H128 + H8 + (size_t)(tt) * 64, \
                Bs_s + ((buf) << 14) + (h) * 8192 + w * 1024 + 512); \
} while (0)

#define LDA(m, ks) (*reinterpret_cast<const bf16x8*>( \
    Ab + aRow + ((m) & 3) * 1024 + ((m) >> 2) * 8192 + ((ks) ? cK1 : cK0)))
#define LDB(n, ks) (*reinterpret_cast<const bf16x8*>( \
    Bb + bRow + (n) * 1024 + ((ks) ? cK1 : cK0)))

// one quadrant: 4 m-frags (mbase..mbase+3) x 4 n-frags, single ks
#define MFMA_QUAD(mbase, A0, A1, A2, A3, BK0, BK1, BK2, BK3) do { \
    acc[(mbase)+0][0] = __builtin_amdgcn_mfma_f32_16x16x32_bf16(A0, BK0, acc[(mbase)+0][0], 0, 0, 0); \
    acc[(mbase)+0][1] = __builtin_amdgcn_mfma_f32_16x16x32_bf16(A0, BK1, acc[(mbase)+0][1], 0, 0, 0); \
    acc[(mbase)+0][2] = __builtin_amdgcn_mfma_f32_16x16x32_bf16(A0, BK2, acc[(mbase)+0][2], 0, 0, 0); \
    acc[(mbase)+0][3] = __builtin_amdgcn_mfma_f32_16x16x32_bf16(A0, BK3, acc[(mbase)+0][3], 0, 0, 0); \
    acc[(mbase)+1][0] = __builtin_amdgcn_mfma_f32_16x16x32_bf16(A1, BK0, acc[(mbase)+1][0], 0, 0, 0); \
    acc[(mbase)+1][1] = __builtin_amdgcn_mfma_f32_16x16x32_bf16(A1, BK1, acc[(mbase)+1][1], 0, 0, 0); \
    acc[(mbase)+1][2] = __builtin_amdgcn_mfma_f32_16x16x32_bf16(A1, BK2, acc[(mbase)+1][2], 0, 0, 0); \
    acc[(mbase)+1][3] = __builtin_amdgcn_mfma_f32_16x16x32_bf16(A1, BK3, acc[(mbase)+1][3], 0, 0, 0); \
    acc[(mbase)+2][0] = __builtin_amdgcn_mfma_f32_16x16x32_bf16(A2, BK0, acc[(mbase)+2][0], 0, 0, 0); \
    acc[(mbase)+2][1] = __builtin_amdgcn_mfma_f32_16x16x32_bf16(A2, BK1, acc[(mbase)+2][1], 0, 0, 0); \
    acc[(mbase)+2][2] = __builtin_amdgcn_mfma_f32_16x16x32_bf16(A2, BK2, acc[(mbase)+2][2], 0, 0, 0); \
    acc[(mbase)+2][3] = __builtin_amdgcn_mfma_f32_16x16x32_bf16(A2, BK3, acc[(mbase)+2][3], 0, 0, 0); \
    acc[(mbase)+3][0] = __builtin_amdgcn_mfma_f32_16x16x32_bf16(A3, BK0, acc[(mbase)+3][0], 0, 0, 0); \
    acc[(mbase)+3][1] = __builtin_amdgcn_mfma_f32_16x16x32_bf16(A3, BK1, acc[(mbase)+3][1], 0, 0, 0); \
    acc[(mbase)+3][2] = __builtin_amdgcn_mfma_f32_16x16x32_bf16(A3, BK2, acc[(mbase)+3][2], 0, 0, 0); \
    acc[(mbase)+3][3] = __builtin_amdgcn_mfma_f32_16x16x32_bf16(A3, BK3, acc[(mbase)+3][3], 0, 0, 0); \
} while (0)

__global__ __launch_bounds__(512, 2) void ce_gemm_bf16_256(
    const short* __restrict__ inp, const short* __restrict__ wgt,
    const int* __restrict__ target,
    float* __restrict__ pm, float* __restrict__ ps, float* __restrict__ tgt,
    int H, int Mt, int Vt)
{
    __shared__ __align__(16) char smem[131072];
    short* As_s = (short*)smem;              // [2][256][64] bf16 = 64 KiB
    short* Bs_s = (short*)(smem + 65536);    // 64 KiB

    const int NT = H >> 6;   // K-tiles

    // bijective XCD swizzle; mt fastest within an XCD chunk
    const int nwg = Mt * Vt;
    const int orig = blockIdx.x;
    const int q8 = nwg >> 3, r8 = nwg & 7;
    const int xcd = orig & 7, idx = orig >> 3;
    const int wg = (xcd < r8 ? xcd * (q8 + 1) : r8 * (q8 + 1) + (xcd - r8) * q8) + idx;
    const int vt = wg / Mt;
    const int mt = wg - vt * Mt;
    const int m0 = mt * 256;
    const int v0 = vt * 256;

    const int tid  = threadIdx.x;
    const int lane = tid & 63;
    const int w    = tid >> 6;     // wave 0..7
    const int wr   = w >> 2;       // 0..1 row-wave
    const int wc   = w & 3;        // 0..3 col-wave

    const size_t H8   = (size_t)H * 8;
    const size_t H128 = (size_t)H * 128;

    // staging source (global, pre-swizzled chunk)
    const short* aSrc = inp + (size_t)(m0 + w * 16 + (lane >> 3)) * H
                        + ((lane & 7) ^ (lane >> 3)) * 8;
    const short* bSrc = wgt + (size_t)(v0 + w * 16 + (lane >> 3)) * H
                        + ((lane & 7) ^ (lane >> 3)) * 8;

    // read-side per-lane offsets (shorts)
    const int aRow = (wr * 64 + (lane & 15)) * 64;
    const int bRow = (wc * 64 + (lane & 15)) * 64;
    const int cK0 = ((lane >> 4) ^ (lane & 7)) * 8;
    const int cK1 = ((4 | (lane >> 4)) ^ (lane & 7)) * 8;

    f32x4 acc[8][4] = {};

    // ---- prologue: stage tile 0; vmcnt(2) leaves Ah1[0] in flight ----
    STAGE_B(0, 0, 0);
    STAGE_B(0, 1, 0);
    STAGE_A(0, 0, 0);
    STAGE_A(0, 1, 0);
    asm volatile("s_waitcnt vmcnt(2)" ::: "memory");
    __builtin_amdgcn_s_barrier();
    __builtin_amdgcn_sched_barrier(0);

    for (int t = 0; t < NT; ++t) {
        const int cur = t & 1, nxt = cur ^ 1;
        const short* Ab = As_s + (cur << 14);
        const short* Bb = Bs_s + (cur << 14);
        const bool pf = (t + 1 < NT);

        // ---- reads for ph0 (8): B ks0 + A m0-3 ks0 ----
        bf16x8 b00 = LDB(0, 0), b10 = LDB(1, 0), b20 = LDB(2, 0), b30 = LDB(3, 0);
        bf16x8 a0 = LDA(0, 0), a1 = LDA(1, 0), a2 = LDA(2, 0), a3 = LDA(3, 0);

        // drain Ah1[cur] (2 outstanding, issued a full tile ago -> free)
        asm volatile("s_waitcnt vmcnt(0)" ::: "memory");

        // ---- reads for ph1 (4): A m4-7 ks0 ; stage Bh0[t+1] ; MFMA ph0 ----
        bf16x8 a4 = LDA(4, 0), a5 = LDA(5, 0), a6 = LDA(6, 0), a7 = LDA(7, 0);
        if (pf) STAGE_B(nxt, 0, t + 1);
        __builtin_amdgcn_s_setprio(1);
        MFMA_QUAD(0, a0, a1, a2, a3, b00, b10, b20, b30);   // ph0
        __builtin_amdgcn_s_setprio(0);

        // ---- reads for ph2 (8): B ks1 + A m0-3 ks1 ; stage Bh1[t+1] ; MFMA ph1
        bf16x8 b01 = LDB(0, 1), b11 = LDB(1, 1), b21 = LDB(2, 1), b31 = LDB(3, 1);
        bf16x8 c0 = LDA(0, 1), c1 = LDA(1, 1), c2 = LDA(2, 1), c3 = LDA(3, 1);
        if (pf) STAGE_B(nxt, 1, t + 1);
        __builtin_amdgcn_s_setprio(1);
        MFMA_QUAD(4, a4, a5, a6, a7, b00, b10, b20, b30);   // ph1
        __builtin_amdgcn_s_setprio(0);

        // ---- reads for ph3 (4): A m4-7 ks1 ; stage Ah0[t+1] ; MFMA ph2 ----
        bf16x8 c4 = LDA(4, 1), c5 = LDA(5, 1), c6 = LDA(6, 1), c7 = LDA(7, 1);
        if (pf) STAGE_A(nxt, 0, t + 1);
        __builtin_amdgcn_s_setprio(1);
        MFMA_QUAD(0, c0, c1, c2, c3, b01, b11, b21, b31);   // ph2
        __builtin_amdgcn_s_setprio(0);

        // ---- stage Ah1[t+1] ; MFMA ph3 ; boundary ----
        if (pf) STAGE_A(nxt, 1, t + 1);
        __builtin_amdgcn_s_setprio(1);
        MFMA_QUAD(4, c4, c5, c6, c7, b01, b11, b21, b31);   // ph3
        __builtin_amdgcn_s_setprio(0);
        asm volatile("s_waitcnt vmcnt(2)" ::: "memory");
        __builtin_amdgcn_s_barrier();
        __builtin_amdgcn_sched_barrier(0);
    }

    // ================= epilogue: fused CE partials =========================
    float* lmax = (float*)smem;
    float* lsum = (float*)(smem + 4096);
    int*   st   = (int*)(smem + 8192);
    __syncthreads();
    if (tid < 256) st[tid] = target[m0 + tid];
    __syncthreads();

    const int g = lane >> 4, c0e = lane & 15;
    #pragma unroll
    for (int m = 0; m < 8; ++m) {
        const int rowbase = ((m >> 2) * 128) + wr * 64 + (m & 3) * 16;
        #pragma unroll
        for (int j = 0; j < 4; ++j) {
            const int row = rowbase + g * 4 + j;
            float vmax = fmaxf(fmaxf(acc[m][0][j], acc[m][1][j]),
                               fmaxf(acc[m][2][j], acc[m][3][j]));
            #pragma unroll
            for (int d = 1; d < 16; d <<= 1)
                vmax = fmaxf(vmax, __shfl_xor(vmax, d));
            float s = 0.f;
            #pragma unroll
            for (int n = 0; n < 4; ++n)
                s += expf(acc[m][n][j] - vmax);
            #pragma unroll
            for (int d = 1; d < 16; d <<= 1)
                s += __shfl_xor(s, d);
            const int tg = st[row];
            #pragma unroll
            for (int n = 0; n < 4; ++n) {
                if (v0 + wc * 64 + n * 16 + c0e == tg)
                    tgt[m0 + row] = acc[m][n][j];
            }
            if (c0e == 0) { lmax[wc * 256 + row] = vmax; lsum[wc * 256 + row] = s; }
        }
    }
    __syncthreads();
    if (tid < 256) {
        float M = lmax[tid];
        M = fmaxf(M, lmax[256 + tid]);
        M = fmaxf(M, lmax[512 + tid]);
        M = fmaxf(M, lmax[768 + tid]);
        float S = lsum[tid]       * expf(lmax[tid]       - M)
                + lsum[256 + tid] * expf(lmax[256 + tid] - M)
                + lsum[512 + tid] * expf(lmax[512 + tid] - M)
                + lsum[768 + tid] * expf(lmax[768 + tid] - M);
        const size_t o = (size_t)(m0 + tid) * Vt + vt;
        pm[o] = M;
        ps[o] = S;
    }
}

// ---------------- fallback path: fp32 reg-staged 128^2 --------------------
#define TILE 128
#define BK 64
static __device__ __forceinline__ void stage_tile(
    const float* __restrict__ src, long long ld, int row0, int k0,
    short (*__restrict__ dst)[BK], int tid)
{
    const int r = tid >> 1;
    const int h = (tid & 1) * 32;
    const float* p = src + (long long)(row0 + r) * ld + k0 + h;
    #pragma unroll
    for (int j = 0; j < 4; ++j) {
        f32x4 x = *reinterpret_cast<const f32x4*>(p + j * 8);
        f32x4 y = *reinterpret_cast<const f32x4*>(p + j * 8 + 4);
        bf16x8 v;
        v[0] = f2bf(x[0]); v[1] = f2bf(x[1]); v[2] = f2bf(x[2]); v[3] = f2bf(x[3]);
        v[4] = f2bf(y[0]); v[5] = f2bf(y[1]); v[6] = f2bf(y[2]); v[7] = f2bf(y[3]);
        *reinterpret_cast<bf16x8*>(&dst[r][h + j * 8]) = v;
    }
}

__global__ __launch_bounds__(256, 2) void ce_gemm_partial(
    const float* __restrict__ inp, const float* __restrict__ wgt,
    const int* __restrict__ target,
    float* __restrict__ pm, float* __restrict__ ps, float* __restrict__ tgt,
    int H, int Vt)
{
    __shared__ __align__(16) short As2[TILE][BK];
    __shared__ __align__(16) short Bs2[TILE][BK];
    __shared__ float lmax[2][TILE];
    __shared__ float lsum[2][TILE];
    __shared__ int st[TILE];

    const int tid  = threadIdx.x;
    const int lane = tid & 63;
    const int wid  = tid >> 6;
    const int wrow = wid >> 1;
    const int wcol = wid & 1;
    const int m0 = blockIdx.x * TILE;
    const int v0 = blockIdx.y * TILE;
    const int vt = blockIdx.y;

    if (tid < TILE) st[tid] = target[m0 + tid];

    f32x4 acc[4][4] = {};

    for (int k0 = 0; k0 < H; k0 += BK) {
        stage_tile(inp, H, m0, k0, As2, tid);
        stage_tile(wgt, H, v0, k0, Bs2, tid);
        __syncthreads();
        #pragma unroll
        for (int ks = 0; ks < 2; ++ks) {
            const int kk = ks * 32 + ((lane >> 4) << 3);
            bf16x8 a[4], b[4];
            #pragma unroll
            for (int m = 0; m < 4; ++m)
                a[m] = *reinterpret_cast<const bf16x8*>(&As2[wrow * 64 + m * 16 + (lane & 15)][kk]);
            #pragma unroll
            for (int n = 0; n < 4; ++n)
                b[n] = *reinterpret_cast<const bf16x8*>(&Bs2[wcol * 64 + n * 16 + (lane & 15)][kk]);
            #pragma unroll
            for (int m = 0; m < 4; ++m)
                #pragma unroll
                for (int n = 0; n < 4; ++n)
                    acc[m][n] = __builtin_amdgcn_mfma_f32_16x16x32_bf16(a[m], b[n], acc[m][n], 0, 0, 0);
        }
        __syncthreads();
    }

    const int g = lane >> 4, c0 = lane & 15;
    #pragma unroll
    for (int m = 0; m < 4; ++m) {
        #pragma unroll
        for (int j = 0; j < 4; ++j) {
            float vmax = fmaxf(fmaxf(acc[m][0][j], acc[m][1][j]),
                               fmaxf(acc[m][2][j], acc[m][3][j]));
            #pragma unroll
            for (int d = 1; d < 16; d <<= 1)
                vmax = fmaxf(vmax, __shfl_xor(vmax, d));
            float s = 0.f;
            #pragma unroll
            for (int n = 0; n < 4; ++n)
                s += expf(acc[m][n][j] - vmax);
            #pragma unroll
            for (int d = 1; d < 16; d <<= 1)
                s += __shfl_xor(s, d);
            const int row = wrow * 64 + m * 16 + g * 4 + j;
            const int t = st[row];
            #pragma unroll
            for (int n = 0; n < 4; ++n) {
                if (v0 + wcol * 64 + n * 16 + c0 == t)
                    tgt[m0 + row] = acc[m][n][j];
            }
            if (c0 == 0) { lmax[wcol][row] = vmax; lsum[wcol][row] = s; }
        }
    }
    __syncthreads();
    if (tid < TILE) {
        const float ma = lmax[0][tid], mb = lmax[1][tid];
        const float M = fmaxf(ma, mb);
        const float S = lsum[0][tid] * expf(ma - M) + lsum[1][tid] * expf(mb - M);
        const size_t idx = (size_t)(m0 + tid) * Vt + vt;
        pm[idx] = M;
        ps[idx] = S;
    }
}

// ---------------- reductions ----------------------------------------------
__global__ void ce_reduce_rows(
    const float* __restrict__ pm, const float* __restrict__ ps,
    const float* __restrict__ tgt, const int* __restrict__ target,
    float* __restrict__ rownll, float* __restrict__ rowvalid, int Vt, int V)
{
    const int row = blockIdx.x;
    const int lane = threadIdx.x;
    float m = -1e30f, s = 0.f;
    for (int vt = lane; vt < Vt; vt += 64) {
        const size_t idx = (size_t)row * Vt + vt;
        const float pmv = pm[idx], psv = ps[idx];
        const float M = fmaxf(m, pmv);
        s = s * expf(m - M) + psv * expf(pmv - M);
        m = M;
    }
    #pragma unroll
    for (int d = 1; d < 64; d <<= 1) {
        const float om = __shfl_xor(m, d), os = __shfl_xor(s, d);
        const float M = fmaxf(m, om);
        s = s * expf(m - M) + os * expf(om - M);
        m = M;
    }
    if (lane == 0) {
        const int t = target[row];
        const bool valid = (t >= 0 && t < V);
        rownll[row]   = valid ? (m + logf(s) - tgt[row]) : 0.f;
        rowvalid[row] = valid ? 1.f : 0.f;
    }
}

__global__ void ce_final(
    const float* __restrict__ rownll, const float* __restrict__ rowvalid,
    float* __restrict__ out, int BT)
{
    __shared__ float ssum[256];
    __shared__ float scnt[256];
    const int tid = threadIdx.x;
    float a = 0.f, c = 0.f;
    for (int i = tid; i < BT; i += 256) { a += rownll[i]; c += rowvalid[i]; }
    ssum[tid] = a; scnt[tid] = c;
    __syncthreads();
    for (int d = 128; d; d >>= 1) {
        if (tid < d) { ssum[tid] += ssum[tid + d]; scnt[tid] += scnt[tid + d]; }
        __syncthreads();
    }
    if (tid == 0) out[0] = ssum[0] / fmaxf(scnt[0], 1.f);
}

extern "C" void kernel_launch(void* const* d_in, const int* in_sizes, int n_in,
                              void* d_out, int out_size, void* d_ws, size_t ws_size,
                              hipStream_t stream) {
    (void)n_in; (void)out_size;
    const float* inp    = (const float*)d_in[0];
    const float* wgt    = (const float*)d_in[1];
    const int*   target = (const int*)d_in[2];
    float* out = (float*)d_out;

    const int BT = in_sizes[2];
    const int H  = in_sizes[0] / BT;
    const int V  = (int)((long long)in_sizes[1] / H);

    const size_t wbf_bytes = (size_t)V * H * 2;
    const size_t ibf_bytes = (size_t)BT * H * 2;

    const bool ok256 = (BT % 256 == 0) && (V % 256 == 0) && (H % 64 == 0) && (H >= 192);

    char* ws = (char*)d_ws;
    if (ok256) {
        const int Mt = BT / 256;   // 16
        const int Vt = V / 256;    // 125
        const size_t pm_bytes = (size_t)BT * Vt * 4;
        const size_t small    = (size_t)BT * 4;
        const size_t need = wbf_bytes + ibf_bytes + 2 * pm_bytes + 3 * small;
        if (ws_size >= need) {
            short* wbf = (short*)ws;                      size_t o = wbf_bytes;
            short* ibf = (short*)(ws + o);                o += ibf_bytes;
            float* pm       = (float*)(ws + o);           o += pm_bytes;
            float* ps       = (float*)(ws + o);           o += pm_bytes;
            float* tgt      = (float*)(ws + o);           o += small;
            float* rownll   = (float*)(ws + o);           o += small;
            float* rowvalid = (float*)(ws + o);

            cvt_f32_bf16<<<2048, 256, 0, stream>>>(wgt, wbf, (long long)V * H);
            cvt_f32_bf16<<<512, 256, 0, stream>>>(inp, ibf, (long long)BT * H);
            ce_gemm_bf16_256<<<Mt * Vt, 512, 0, stream>>>(ibf, wbf, target, pm, ps, tgt, H, Mt, Vt);
            ce_reduce_rows<<<BT, 64, 0, stream>>>(pm, ps, tgt, target, rownll, rowvalid, Vt, V);
            ce_final<<<1, 256, 0, stream>>>(rownll, rowvalid, out, BT);
            return;
        }
    }
    // fallback: fp32 reg-staged 128^2
    {
        const int Mt = BT / TILE;
        const int Vt = V / TILE;
        const size_t pm_bytes = (size_t)BT * Vt * 4;
        const size_t small    = (size_t)BT * 4;
        float* pm       = (float*)ws;                 size_t o = pm_bytes;
        float* ps       = (float*)(ws + o);           o += pm_bytes;
        float* tgt      = (float*)(ws + o);           o += small;
        float* rownll   = (float*)(ws + o);           o += small;
        float* rowvalid = (float*)(ws + o);

        dim3 grid(Mt, Vt);
        ce_gemm_partial<<<grid, 256, 0, stream>>>(inp, wgt, target, pm, ps, tgt, H, Vt);
        ce_reduce_rows<<<BT, 64, 0, stream>>>(pm, ps, tgt, target, rownll, rowvalid, Vt, V);
        ce_final<<<1, 256, 0, stream>>>(rownll, rowvalid, out, BT);
    }
}